// Round 7
// baseline (282.825 us; speedup 1.0000x reference)
//
#include <hip/hip_runtime.h>

// Problem constants
#define BSEQ 64
#define LSEQ 512
#define CCH  1024
#define NT   7            // NUM_TAGS
#define NC   5            // real classes (labels are always 0..4)
#define NTOK (BSEQ*LSEQ)  // 32768
#define START_TAG 5
#define STOP_TAG  6
#define NEGV (-10000.0f)
#define GRID_LOGITS 1024  // fallback k_logits grid
#define FGRID 1024        // fused grid: 1024 blocks x 256 thr (no co-residency needed)
#define FBLK  256
#define MAGIC 0x5A17C0DEu // flag value; collides with no plausible poison pattern

// workspace layout (float indices)
#define WS_M   0          // [1024][32] chunk matrices (25 used per chunk)
#define WS_G   32768      // [1024] gold partials
#define WS_U   33792      // [64][8] u vectors (5 used)
#define WS_PS  34304      // [64] per-batch partial scores
#define WS_CF  34368      // [1024] chunk flags (uint)
#define WS_FF  35392      // [64] fold flags (uint)
#define WS_TOT 35456

typedef float vfloat4 __attribute__((ext_vector_type(4)));

// ---- device-scope publish/consume (no reliance on cross-XCD L2 coherence) ----
__device__ __forceinline__ void ws_store(float* p, float v) {
    atomicExch((unsigned int*)p, __float_as_uint(v));
}
__device__ __forceinline__ float ws_load(float* p) {
    return __uint_as_float(atomicAdd((unsigned int*)p, 0u));
}
__device__ __forceinline__ unsigned flag_read(float* p) {
    return atomicAdd((unsigned int*)p, 0u);
}
__device__ __forceinline__ void flag_write(float* p, unsigned v) {
    atomicExch((unsigned int*)p, v);
}

// ---------------- DPP wave64 sum (result lands in lane 63) ----------------
template<int CTRL, int RMASK, int BMASK>
__device__ __forceinline__ float dpp_add(float x) {
    int y = __builtin_amdgcn_update_dpp(0, __float_as_int(x), CTRL, RMASK, BMASK, true);
    return x + __int_as_float(y);
}
__device__ __forceinline__ float wave_sum(float x) {
    x = dpp_add<0x111, 0xF, 0xF>(x);  // row_shr:1
    x = dpp_add<0x112, 0xF, 0xF>(x);  // row_shr:2
    x = dpp_add<0x114, 0xF, 0xF>(x);  // row_shr:4
    x = dpp_add<0x118, 0xF, 0xF>(x);  // row_shr:8
    x = dpp_add<0x142, 0xA, 0xF>(x);  // row_bcast:15 into rows 1,3
    x = dpp_add<0x143, 0xC, 0xF>(x);  // row_bcast:31 into rows 2,3 -> lane63 = total
    return x;
}

// 5-way log-sum-exp helper
__device__ __forceinline__ float lse5(const float v0, const float v1, const float v2,
                                      const float v3, const float v4) {
    float m = fmaxf(fmaxf(fmaxf(v0, v1), fmaxf(v2, v3)), v4);
    float s = __expf(v0 - m) + __expf(v1 - m) + __expf(v2 - m)
            + __expf(v3 - m) + __expf(v4 - m);
    return m + __logf(s);
}

// ================= FUSED kernel (single plain dispatch) =================
// R10: R6's cooperative attempt was unverifiable (211.7 = fallback band).
// This version needs NO cooperative launch and NO co-residency: flag-based
// producer-consumer. 1024 blocks each: logits for 32 contiguous rows (proven
// floor-hitting stream structure) -> chunk 5x5 matrix + gold partial + u ->
// publish to ws via device-scope atomics -> set MAGIC flag. 64 fold blocks
// (sub==0) spin on their batch's 16 flags (spinners<=65 << 256 CU slots,
// producers never wait -> deadlock-free under any dispatch order, G16-safe),
// fold 16 matrices in-wave via shfl (no LDS, no barrier), publish partial;
// block 0 spins on 64 fold flags and writes out[0] once (no init race).
// Flags consumed-then-reset; MAGIC != any plausible poison -> no init node.
__global__ __launch_bounds__(256)
void k_fused(const float* __restrict__ X, const float* __restrict__ W,
             const float* __restrict__ bvec, const int* __restrict__ lab,
             const float* __restrict__ trans, float* __restrict__ out,
             float* __restrict__ ws)
{
    __shared__ float Wl[NT][CCH];   // 28 KB
    __shared__ float bl[NT];
    __shared__ float Tl[49];
    __shared__ float E_lds[32][5];  // this block's emissions (classes 0..4, incl bias)
    __shared__ float Msub[4*25];    // 4 sub-chunk matrices
    __shared__ float Cb[2*25];      // combine round 1

    const int tid  = threadIdx.x;
    const int lane = tid & 63;
    const int wv   = tid >> 6;      // 0..3
    const int bx   = blockIdx.x;
    const int sub  = bx & 15;       // chunk index within batch
    const int bat  = bx >> 4;

    vfloat4 xb[3][4];   // [phase-slot][row j]
    const size_t rbase = (size_t)bx * 32 + wv;       // + m*4, m=0..7

    #define ISSUE_PHASE(p, slot)                                                    \
        if ((p) < 8) {                                                              \
            const int G_ = (p) >> 2, k_ = (p) & 3;                                  \
            _Pragma("unroll")                                                       \
            for (int j = 0; j < 4; j++) {                                           \
                const size_t row_ = rbase + (size_t)((G_*4 + j) * 4);               \
                const vfloat4* xp_ = (const vfloat4*)(X + row_ * CCH) + (k_*64 + lane); \
                xb[slot][j] = __builtin_nontemporal_load(xp_);                      \
            }                                                                       \
        }

    ISSUE_PHASE(0, 0)
    ISSUE_PHASE(1, 1)

    {
        const vfloat4* W4  = (const vfloat4*)W;
        vfloat4*       Wl4 = (vfloat4*)(&Wl[0][0]);
        for (int i = tid; i < NT*CCH/4; i += FBLK) Wl4[i] = W4[i];
        if (tid < NT) bl[tid] = bvec[tid];
        if (tid < 49) Tl[tid] = trans[tid];
        const int gidx = bx * FBLK + tid;            // labels copy (blocks 0..127)
        if (gidx < NTOK) out[1 + gidx] = (float)lab[gidx];
    }
    __syncthreads();

    float* outP = out + 1 + NTOK;

    float acc[4][NT];
    #pragma unroll
    for (int j = 0; j < 4; j++)
        #pragma unroll
        for (int t = 0; t < NT; t++) acc[j][t] = 0.0f;

    #pragma unroll
    for (int p = 0; p < 8; ++p) {
        const int slot = p % 3;
        const int k    = p & 3;

        ISSUE_PHASE(p + 2, (p + 2) % 3)

        vfloat4 wreg[NT];
        {
            const int cb = (k*64 + lane) * 4;
            #pragma unroll
            for (int t = 0; t < NT; t++)
                wreg[t] = *(const vfloat4*)(&Wl[t][cb]);
        }

        #pragma unroll
        for (int j = 0; j < 4; j++) {
            #pragma unroll
            for (int t = 0; t < NT; t++) {
                acc[j][t] = fmaf(xb[slot][j].x, wreg[t].x,
                            fmaf(xb[slot][j].y, wreg[t].y,
                            fmaf(xb[slot][j].z, wreg[t].z,
                            fmaf(xb[slot][j].w, wreg[t].w, acc[j][t]))));
            }
        }

        if (k == 3) {
            const int G = p >> 2;
            #pragma unroll
            for (int j = 0; j < 4; j++) {
                const int m = G*4 + j;
                const size_t row = rbase + (size_t)(m * 4);
                const int rloc = wv + m*4;
                #pragma unroll
                for (int t = 0; t < NT; t++) {
                    float s = wave_sum(acc[j][t]);
                    if (lane == 63) {
                        const float e = s + bl[t];
                        outP[row * NT + t] = e;
                        if (t < NC) E_lds[rloc][t] = e;
                    }
                    acc[j][t] = 0.0f;
                }
            }
        }
    }
    #undef ISSUE_PHASE

    __syncthreads();   // E_lds complete

    // ---------------- per-block CRF chunk work (waves specialize) ----------------
    if (wv == 0) {
        // 4 sub-chunks x 8 steps x 5 basis on lanes 0..19
        if (lane < 20) {
            const int sc = lane / 5, basis = lane - sc*5;
            float TR[25];
            #pragma unroll
            for (int j = 0; j < NC; j++)
                #pragma unroll
                for (int k = 0; k < NC; k++) TR[j*5+k] = Tl[j*7+k];
            float fv[5];
            #pragma unroll
            for (int j = 0; j < NC; j++) fv[j] = (j == basis) ? 0.0f : NEGV;
            const int s0 = (sub == 0 && sc == 0) ? 1 : sc*8;  // batch token 0 via u
            const int s1 = sc*8 + 8;
            for (int s = s0; s < s1; ++s) {
                float fn[5];
                #pragma unroll
                for (int j = 0; j < NC; j++)
                    fn[j] = lse5(fv[0]+TR[j*5+0], fv[1]+TR[j*5+1], fv[2]+TR[j*5+2],
                                 fv[3]+TR[j*5+3], fv[4]+TR[j*5+4]) + E_lds[s][j];
                #pragma unroll
                for (int j = 0; j < NC; j++) fv[j] = fn[j];
            }
            #pragma unroll
            for (int j = 0; j < NC; j++) Msub[sc*25 + basis*5 + j] = fv[j];
        }
        // combine 4 -> 2 -> 1 (single wave: program order gives LDS ordering)
        if (lane < 50) {
            const int pp = lane / 25, r = lane - pp*25, i = r/5, jj = r - (r/5)*5;
            const float* A = &Msub[(2*pp)*25 + i*5];
            const float* B = &Msub[(2*pp+1)*25 + jj];
            Cb[pp*25 + r] = lse5(A[0]+B[0], A[1]+B[5], A[2]+B[10], A[3]+B[15], A[4]+B[20]);
        }
        if (lane < 25) {
            const int i = lane/5, jj = lane - i*5;
            const float* A = &Cb[i*5];
            const float* B = &Cb[25 + jj];
            ws_store(&ws[WS_M + (size_t)bx*32 + lane],
                     lse5(A[0]+B[0], A[1]+B[5], A[2]+B[10], A[3]+B[15], A[4]+B[20]));
        }
    } else if (wv == 1) {
        // gold partial for this block's 32 tokens
        float g = 0.0f;
        if (lane < 32) {
            const int lg = bx*32 + lane;
            const int t  = lab[lg];
            const int tp = ((lg & (LSEQ-1)) == 0) ? START_TAG : lab[lg - 1];
            g = E_lds[lane][t] + Tl[t*7 + tp];
        }
        float gs = wave_sum(g);
        if (lane == 63) ws_store(&ws[WS_G + bx], gs);
    } else if (wv == 2) {
        // u injection (batch token 0) from the batch's first block
        if (sub == 0 && lane < NC)
            ws_store(&ws[WS_U + bat*8 + lane], Tl[lane*7 + START_TAG] + E_lds[0][lane]);
    }

    __syncthreads();   // all publishes issued & drained (barrier waits vmcnt)
    if (tid == 0) {
        __threadfence();
        flag_write(&ws[WS_CF + bx], MAGIC);
    }

    // ---------------- level 1: per-batch fold (blocks with sub==0, wave 0) ----------------
    if (sub == 0 && wv == 0) {
        if (lane < 16) {
            while (flag_read(&ws[WS_CF + bat*16 + lane]) != MAGIC)
                __builtin_amdgcn_s_sleep(8);
            flag_write(&ws[WS_CF + bat*16 + lane], 0u);  // consume-then-reset
        }
        __threadfence();

        // prefetch 16 chunk matrices: lane e<25 holds entry e of each (static idx)
        float Mm[16];
        #pragma unroll
        for (int m = 0; m < 16; ++m)
            Mm[m] = (lane < 25) ? ws_load(&ws[WS_M + ((size_t)bat*16 + m)*32 + lane]) : 0.0f;

        float gp = (lane < 16) ? ws_load(&ws[WS_G + bat*16 + lane]) : 0.0f;
        float gtot = wave_sum(gp);
        gtot = __shfl(gtot, 63);

        // fold: fvr on lanes 0..4 (state j = lane); M[k][j] = shfl(Mm, k*5+j)
        float fvr = (lane < NC) ? ws_load(&ws[WS_U + bat*8 + lane]) : 0.0f;
        #pragma unroll
        for (int m = 0; m < 16; ++m) {
            const float f0 = __shfl(fvr, 0), f1 = __shfl(fvr, 1), f2 = __shfl(fvr, 2),
                        f3 = __shfl(fvr, 3), f4 = __shfl(fvr, 4);
            const float t0 = __shfl(Mm[m], 0*5 + lane);
            const float t1 = __shfl(Mm[m], 1*5 + lane);
            const float t2 = __shfl(Mm[m], 2*5 + lane);
            const float t3 = __shfl(Mm[m], 3*5 + lane);
            const float t4 = __shfl(Mm[m], 4*5 + lane);
            fvr = lse5(f0 + t0, f1 + t1, f2 + t2, f3 + t3, f4 + t4);
        }
        const float v0 = __shfl(fvr, 0), v1 = __shfl(fvr, 1), v2 = __shfl(fvr, 2),
                    v3 = __shfl(fvr, 3), v4 = __shfl(fvr, 4);
        if (lane == 0) {
            float fwd = lse5(v0 + Tl[STOP_TAG*7+0], v1 + Tl[STOP_TAG*7+1],
                             v2 + Tl[STOP_TAG*7+2], v3 + Tl[STOP_TAG*7+3],
                             v4 + Tl[STOP_TAG*7+4]);
            float gold = gtot + Tl[STOP_TAG*7 + lab[bat*LSEQ + LSEQ - 1]];
            ws_store(&ws[WS_PS + bat], fwd - gold);
            __threadfence();
            flag_write(&ws[WS_FF + bat], MAGIC);
        }
    }

    // ---------------- level 2: block 0 sums 64 partials, writes score once ----------------
    if (bx == 0 && wv == 0) {
        while (flag_read(&ws[WS_FF + lane]) != MAGIC)   // one flag per lane (64)
            __builtin_amdgcn_s_sleep(8);
        flag_write(&ws[WS_FF + lane], 0u);
        __threadfence();
        float ps = ws_load(&ws[WS_PS + lane]);
        float tot = wave_sum(ps);
        if (lane == 63) out[0] = tot;   // single writer, no init needed
    }
}

// ================= FALLBACK path (proven R3 two-kernel) =================
__global__ __launch_bounds__(256)
void k_logits(const float* __restrict__ X, const float* __restrict__ W,
              const float* __restrict__ bvec, const int* __restrict__ lab,
              float* __restrict__ out)
{
    __shared__ float Wl[NT][CCH];
    __shared__ float bl[NT];

    const int lane = threadIdx.x & 63;
    const int wid  = (blockIdx.x * 256 + threadIdx.x) >> 6;
    const int nw   = (GRID_LOGITS * 256) >> 6;

    vfloat4 xb[3][4];

    #define ISSUE_PHASE(p, slot)                                                   \
        if ((p) < 8) {                                                             \
            const int G_ = (p) >> 2, k_ = (p) & 3;                                 \
            _Pragma("unroll")                                                      \
            for (int j = 0; j < 4; j++) {                                          \
                const size_t row_ = (size_t)(wid + (G_*4 + j) * nw);               \
                const vfloat4* xp_ = (const vfloat4*)(X + row_ * CCH) + (k_*64 + lane); \
                xb[slot][j] = __builtin_nontemporal_load(xp_);                     \
            }                                                                      \
        }

    ISSUE_PHASE(0, 0)
    ISSUE_PHASE(1, 1)

    {
        const vfloat4* W4  = (const vfloat4*)W;
        vfloat4*       Wl4 = (vfloat4*)(&Wl[0][0]);
        for (int i = threadIdx.x; i < NT*CCH/4; i += 256) Wl4[i] = W4[i];
        if (threadIdx.x < NT) bl[threadIdx.x] = bvec[threadIdx.x];
    }
    __syncthreads();

    float* outP = out + 1 + NTOK;

    float acc[4][NT];
    #pragma unroll
    for (int j = 0; j < 4; j++)
        #pragma unroll
        for (int t = 0; t < NT; t++) acc[j][t] = 0.0f;

    #pragma unroll
    for (int p = 0; p < 8; ++p) {
        const int slot = p % 3;
        const int k    = p & 3;

        ISSUE_PHASE(p + 2, (p + 2) % 3)

        vfloat4 wreg[NT];
        {
            const int cb = (k*64 + lane) * 4;
            #pragma unroll
            for (int t = 0; t < NT; t++)
                wreg[t] = *(const vfloat4*)(&Wl[t][cb]);
        }

        #pragma unroll
        for (int j = 0; j < 4; j++) {
            #pragma unroll
            for (int t = 0; t < NT; t++) {
                acc[j][t] = fmaf(xb[slot][j].x, wreg[t].x,
                            fmaf(xb[slot][j].y, wreg[t].y,
                            fmaf(xb[slot][j].z, wreg[t].z,
                            fmaf(xb[slot][j].w, wreg[t].w, acc[j][t]))));
            }
        }

        if (k == 3) {
            const int G = p >> 2;
            #pragma unroll
            for (int j = 0; j < 4; j++) {
                const size_t row = (size_t)(wid + (G*4 + j) * nw);
                #pragma unroll
                for (int t = 0; t < NT; t++) {
                    float s = wave_sum(acc[j][t]);
                    if (lane == 63) outP[row * NT + t] = s + bl[t];
                    acc[j][t] = 0.0f;
                }
            }
        }
    }
    #undef ISSUE_PHASE

    for (int i = blockIdx.x * 256 + threadIdx.x; i < NTOK; i += GRID_LOGITS * 256)
        out[1 + i] = (float)lab[i];
    if (blockIdx.x == 0 && threadIdx.x == 0) out[0] = 0.0f;
}

__global__ __launch_bounds__(320)
void k_crf(const float* __restrict__ dout_ro, const int* __restrict__ lab,
           const float* __restrict__ trans, float* __restrict__ score)
{
    __shared__ float E[LSEQ*NT];
    __shared__ float M2[32*25];
    __shared__ float T[49];
    __shared__ float u_sh[NC];
    __shared__ float gred[5];

    const int b   = blockIdx.x;
    const int tid = threadIdx.x;
    const float* feats = dout_ro + 1 + NTOK + (size_t)b * (LSEQ*NT);

    for (int i = tid; i < LSEQ*NT; i += 320) E[i] = feats[i];
    if (tid < 49) T[tid] = trans[tid];
    __syncthreads();

    if (tid < NC) u_sh[tid] = T[tid*NT + START_TAG] + E[tid];

    float g = 0.0f;
    for (int l = tid; l < LSEQ; l += 320) {
        const int t  = lab[b*LSEQ + l];
        const int tp = (l == 0) ? START_TAG : lab[b*LSEQ + l - 1];
        g += E[l*NT + t] + T[t*NT + tp];
    }
    if (tid == 0) g += T[STOP_TAG*NT + lab[b*LSEQ + LSEQ - 1]];
    {
        float gs = wave_sum(g);
        if ((tid & 63) == 63) gred[tid >> 6] = gs;
    }

    float TR[NC*NC];
    #pragma unroll
    for (int j = 0; j < NC; j++)
        #pragma unroll
        for (int k = 0; k < NC; k++) TR[j*NC + k] = T[j*NT + k];

    const int chunk = tid / NC;
    const int basis = tid - chunk * NC;
    float fv[NC];
    #pragma unroll
    for (int j = 0; j < NC; j++) fv[j] = (j == basis) ? 0.0f : NEGV;

    const int l0    = (chunk == 0) ? 1 : chunk * 8;
    const int steps = (chunk == 0) ? 7 : 8;
    for (int s = 0; s < steps; s++) {
        const int l = l0 + s;
        float fn[NC];
        #pragma unroll
        for (int j = 0; j < NC; j++) {
            fn[j] = lse5(fv[0] + TR[j*NC+0], fv[1] + TR[j*NC+1], fv[2] + TR[j*NC+2],
                         fv[3] + TR[j*NC+3], fv[4] + TR[j*NC+4]) + E[l*NT + j];
        }
        #pragma unroll
        for (int j = 0; j < NC; j++) fv[j] = fn[j];
    }
    __syncthreads();
    #pragma unroll
    for (int j = 0; j < NC; j++) E[chunk*25 + basis*NC + j] = fv[j];

    int n = 64, cur = 0;
    while (n > 1) {
        __syncthreads();
        const float* in = (cur == 0) ? (const float*)E : (const float*)M2;
        float*       ob = (cur == 0) ? M2 : E;
        const int half = n >> 1;
        for (int e2 = tid; e2 < half*25; e2 += 320) {
            const int p = e2 / 25, r = e2 - p*25;
            const int i = r / NC, j = r - (r/NC)*NC;
            const float* A  = in + (2*p)*25 + i*NC;
            const float* Bm = in + (2*p + 1)*25 + j;
            ob[p*25 + r] = lse5(A[0] + Bm[0], A[1] + Bm[NC], A[2] + Bm[2*NC],
                                A[3] + Bm[3*NC], A[4] + Bm[4*NC]);
        }
        cur ^= 1; n = half;
    }
    __syncthreads();

    if (tid == 0) {
        float gg = gred[0] + gred[1] + gred[2] + gred[3] + gred[4];
        const float* M = (cur == 0) ? (const float*)E : (const float*)M2;
        float v[NC];
        #pragma unroll
        for (int j = 0; j < NC; j++)
            v[j] = lse5(u_sh[0] + M[0*NC+j], u_sh[1] + M[1*NC+j], u_sh[2] + M[2*NC+j],
                        u_sh[3] + M[3*NC+j], u_sh[4] + M[4*NC+j]);
        float fwd = lse5(v[0] + T[STOP_TAG*NT+0], v[1] + T[STOP_TAG*NT+1],
                         v[2] + T[STOP_TAG*NT+2], v[3] + T[STOP_TAG*NT+3],
                         v[4] + T[STOP_TAG*NT+4]);
        atomicAdd(score, fwd - gg);
    }
}

extern "C" void kernel_launch(void* const* d_in, const int* in_sizes, int n_in,
                              void* d_out, int out_size, void* d_ws, size_t ws_size,
                              hipStream_t stream) {
    const float* X     = (const float*)d_in[0];   // fuse_embeddings [32768,1024]
    const int*   lab   = (const int*)  d_in[1];   // label_class [32768]
    const float* W     = (const float*)d_in[2];   // [7,1024]
    const float* bvec  = (const float*)d_in[3];   // [7]
    const float* trans = (const float*)d_in[4];   // [7,7]
    float* out = (float*)d_out;
    float* wsf = (float*)d_ws;

    if (wsf != nullptr && ws_size >= (size_t)WS_TOT * sizeof(float)) {
        k_fused<<<FGRID, FBLK, 0, stream>>>(X, W, bvec, lab, trans, out, wsf);
        return;
    }

    // Fallback: proven two-kernel path (ws unavailable)
    k_logits<<<GRID_LOGITS, 256, 0, stream>>>(X, W, bvec, lab, out);
    k_crf<<<BSEQ, 320, 0, stream>>>(out, lab, trans, out);
}